// Round 6
// baseline (125.903 us; speedup 1.0000x reference)
//
#include <hip/hip_runtime.h>
#include <hip/hip_bf16.h>

#define D_DIM 64
#define K_CODES 512

typedef _Float16 half8 __attribute__((ext_vector_type(8)));
typedef float f32x4 __attribute__((ext_vector_type(4)));

// ws layout: ee f32[512] @0 ; ET f32[512*64] @2048 B ; Bimg f16[512*64*2] @133120 B
#define WS_EE_OFF 0
#define WS_ET_OFF 2048
#define WS_BIMG_OFF 133120
#define WS_NEEDED (133120 + 131072)

// global_load_lds: wave-uniform LDS base + lane*16; per-lane global source.
#define GLDS16(gp, lp) __builtin_amdgcn_global_load_lds( \
    (const __attribute__((address_space(1))) unsigned int*)(gp), \
    (__attribute__((address_space(3))) unsigned int*)(lp), 16, 0, 0)

// ---------------- prep: ee, ET (gather layout), Bimg (frag-ordered f16 hi/lo of -2*E) ----
// (proven) thread u: code k = u>>3, dim-chunk dc = u&7. Coalesced half8/f32x4 stores;
// ee reduced over the 8 dc-lanes via shfl_xor. Zeroes the loss accumulator.
// Bimg holds the f16 split of (-2*E) (exact scaling), so the main kernel's MFMA
// accumulates ee - 2*x.e directly when hh is initialized with ee.
__global__ __launch_bounds__(256) void vq3_prep(const float* __restrict__ E,
                                                float* __restrict__ ee,
                                                float* __restrict__ ET,
                                                _Float16* __restrict__ Bimg,
                                                float* __restrict__ loss_ptr) {
    const int u = blockIdx.x * 256 + threadIdx.x;   // [0, 4096)
    if (u == 0) *loss_ptr = 0.f;
    const int k = u >> 3;          // code 0..511
    const int dc = u & 7;          // dim-chunk 0..7
    const int t = k >> 4, n = k & 15;
    const int ks = dc >> 2, g = dc & 3;

    float v[8];
    float s = 0.f;
    half8 hi, lo;
#pragma unroll
    for (int j = 0; j < 8; ++j) {
        float e = E[(size_t)(dc * 8 + j) * K_CODES + k];
        v[j] = e;
        s = fmaf(e, e, s);
        float em = -2.0f * e;                    // exact
        _Float16 h = (_Float16)em;
        hi[j] = h;
        lo[j] = (_Float16)((em - (float)h) * 2048.0f);
    }
    f32x4* etp = (f32x4*)(ET + (size_t)k * D_DIM + dc * 8);
    etp[0] = (f32x4){v[0], v[1], v[2], v[3]};
    etp[1] = (f32x4){v[4], v[5], v[6], v[7]};
    _Float16* bp = Bimg + (size_t)t * 2048 + g * 128 + n * 8;
    *(half8*)(bp + ks * 512) = hi;            // part = ks (hi)
    *(half8*)(bp + (2 + ks) * 512) = lo;      // part = 2+ks (lo, pre-scaled by 2^11)
    s += __shfl_xor(s, 1);
    s += __shfl_xor(s, 2);
    s += __shfl_xor(s, 4);
    if (dc == 0) ee[k] = s;
}

// ---------------- main: LDS-staged B + 4 waves/SIMD, 32 tokens/wave, grid 1024 -----------
// Round-5 post-mortem: __launch_bounds__(256,4) only CAPS regs at 128; the allocator chased
// 8 waves/SIMD (64 VGPR) and spilled ~35 regs into the loop (WRITE 33->57 MB, FETCH
// 18->29 MB of scratch round-trip). Round 4 proved amdgpu_waves_per_eu(N,N) pins the
// allocator to a clean allocation. ONE change vs round 5: pin (4,4). rt=2 live state
// ~100 regs < 128 budget -> no spill possible, no headroom for the 8-wave heuristic.
//  * rt=2 (32 tokens/wave), grid 1024 = 4 blocks/CU = 16 waves/CU = 4 waves/SIMD.
//  * LDS B double-buffer via global_load_lds (proven round 4), 1 barrier/chunk.
//  * LDS 35 KB x 4 blocks = 140 KB <= 160 KB/CU.
__attribute__((amdgpu_waves_per_eu(4, 4)))
__global__ __launch_bounds__(256) void vq3_main(
        const float* __restrict__ x, const float* __restrict__ ee,
        const float* __restrict__ ET, const _Float16* __restrict__ Bimg,
        float* __restrict__ out_q, float* __restrict__ out_loss, float loss_scale) {
    __shared__ __align__(16) _Float16 Bs[2][8192];   // 2 x 4 tiles x 2048 f16 = 32 KB
    __shared__ float ee_s[K_CODES];
    __shared__ int idx_s[128];
    __shared__ float wsum_s[4];

    const int tid = threadIdx.x;
    const int l = tid & 63;            // lane
    const int w = tid >> 6;            // wave in block
    const int g = l >> 4;              // k-group quad (0..3)
    const int n = l & 15;              // A row / B col within tile
    const int bt0 = blockIdx.x * 128;  // block token base
    const int t0 = bt0 + w * 32;       // wave token base (32 tokens/wave)

    // ---- issue chunk-0 staging FIRST (direct to LDS, latency hides under A-frag cvt)
    {
        const char* gsrc = (const char*)Bimg + w * 4096 + l * 16;
        char* ldst = (char*)&Bs[0][0] + w * 4096;          // wave-uniform
#pragma unroll
        for (int i = 0; i < 4; ++i) GLDS16(gsrc + i * 1024, ldst + i * 1024);
    }
    const float e0 = ee[tid], e1 = ee[tid + 256];

    // ---- A fragments: 2 row-tiles x 2 k-steps, hi and lo(x2^11), held in regs all kernel.
    // Also accumulate ||x||^2 per token (xx[rt], reduced over the 4 g-lane-groups).
    half8 Ahi[2][2], Alo[2][2];
    float xx[2];
#pragma unroll
    for (int rt = 0; rt < 2; ++rt) {
        float xs = 0.f;
#pragma unroll
        for (int ks = 0; ks < 2; ++ks) {
            const f32x4* xp = (const f32x4*)(x + (size_t)(t0 + rt * 16 + n) * D_DIM + ks * 32 + g * 8);
            f32x4 a = xp[0], b = xp[1];
            float va[8] = {a[0], a[1], a[2], a[3], b[0], b[1], b[2], b[3]};
            half8 h, lo;
#pragma unroll
            for (int j = 0; j < 8; ++j) {
                _Float16 hj = (_Float16)va[j];
                h[j] = hj;
                lo[j] = (_Float16)((va[j] - (float)hj) * 2048.0f);
                xs = fmaf(va[j], va[j], xs);
            }
            Ahi[rt][ks] = h;
            Alo[rt][ks] = lo;
        }
        xs += __shfl_xor(xs, 16);
        xs += __shfl_xor(xs, 32);
        xx[rt] = xs;
    }

    // ---- commit ee to LDS; barrier covers chunk-0 staging (vmcnt drain) + ee stores
    ee_s[tid] = e0;
    ee_s[tid + 256] = e1;
    __syncthreads();

    // ---- running argmin state (bd holds ee - 2*dot directly)
    float bd[2][4];
    int bi[2][4];
#pragma unroll
    for (int i = 0; i < 2; ++i)
#pragma unroll
        for (int r = 0; r < 4; ++r) { bd[i][r] = 3.4e38f; bi[i][r] = 0; }

    // ---- chunk loop: 8 chunks x 4 tiles; double-buffered LDS, 1 barrier/chunk.
    // Buffer (c+1)&1 was last READ in chunk c-1 (before the previous barrier), so the
    // staging writes issued at the top of chunk c cannot race any reader.
#pragma unroll 1
    for (int c = 0; c < 8; ++c) {
        if (c < 7) {
            const char* gsrc = (const char*)Bimg + (size_t)(c + 1) * 16384 + w * 4096 + l * 16;
            char* ldst = (char*)&Bs[(c + 1) & 1][0] + w * 4096;   // wave-uniform
#pragma unroll
            for (int i = 0; i < 4; ++i) GLDS16(gsrc + i * 1024, ldst + i * 1024);
        }
        const _Float16* bs = &Bs[c & 1][0];
#pragma unroll
        for (int tt = 0; tt < 4; ++tt) {
            const _Float16* tb = bs + tt * 2048 + l * 8;   // lane's 16B slot in each part
            half8 Bh0 = *(const half8*)(tb);
            half8 Bh1 = *(const half8*)(tb + 512);
            half8 Bl0 = *(const half8*)(tb + 1024);
            half8 Bl1 = *(const half8*)(tb + 1536);
            const int tg = c * 4 + tt;                     // global 16-code tile
            const float eev = ee_s[tg * 16 + n];           // broadcast within g-groups
            f32x4 hh[2], cr[2];
#pragma unroll
            for (int rt = 0; rt < 2; ++rt) {
                hh[rt] = (f32x4){eev, eev, eev, eev};      // accumulate ee - 2*dot directly
                cr[rt] = (f32x4){0.f, 0.f, 0.f, 0.f};
            }
#pragma unroll
            for (int rt = 0; rt < 2; ++rt) {
                hh[rt] = __builtin_amdgcn_mfma_f32_16x16x32_f16(Ahi[rt][0], Bh0, hh[rt], 0, 0, 0);
                hh[rt] = __builtin_amdgcn_mfma_f32_16x16x32_f16(Ahi[rt][1], Bh1, hh[rt], 0, 0, 0);
                cr[rt] = __builtin_amdgcn_mfma_f32_16x16x32_f16(Ahi[rt][0], Bl0, cr[rt], 0, 0, 0);
                cr[rt] = __builtin_amdgcn_mfma_f32_16x16x32_f16(Ahi[rt][1], Bl1, cr[rt], 0, 0, 0);
                cr[rt] = __builtin_amdgcn_mfma_f32_16x16x32_f16(Alo[rt][0], Bh0, cr[rt], 0, 0, 0);
                cr[rt] = __builtin_amdgcn_mfma_f32_16x16x32_f16(Alo[rt][1], Bh1, cr[rt], 0, 0, 0);
            }
            const int code = tg * 16 + n;
#pragma unroll
            for (int rt = 0; rt < 2; ++rt)
#pragma unroll
                for (int r = 0; r < 4; ++r) {
                    float s = fmaf(4.8828125e-4f, cr[rt][r], hh[rt][r]);  // hh + cross*2^-11
                    if (s < bd[rt][r]) { bd[rt][r] = s; bi[rt][r] = code; }
                }
        }
        __syncthreads();   // drains this chunk's staging (vmcnt) + all reads of bs
    }

    // ---- cross-lane argmin over the 16 code-columns (reduce over lane bits 0..3)
#pragma unroll
    for (int mask = 1; mask < 16; mask <<= 1) {
#pragma unroll
        for (int rt = 0; rt < 2; ++rt)
#pragma unroll
            for (int r = 0; r < 4; ++r) {
                float od = __shfl_xor(bd[rt][r], mask);
                int oi = __shfl_xor(bi[rt][r], mask);
                if (od < bd[rt][r] || (od == bd[rt][r] && oi < bi[rt][r])) { bd[rt][r] = od; bi[rt][r] = oi; }
            }
    }
    if (n == 0) {
#pragma unroll
        for (int rt = 0; rt < 2; ++rt)
#pragma unroll
            for (int r = 0; r < 4; ++r)
                idx_s[w * 32 + rt * 16 + g * 4 + r] = bi[rt][r];   // C-layout: row = g*4 + r
    }

    // ---- loss WITHOUT re-reading x: dist = bd_min + ||x||^2 (proven in round 2)
    float lsum = 0.f;
#pragma unroll
    for (int rt = 0; rt < 2; ++rt)
#pragma unroll
        for (int r = 0; r < 4; ++r) {
            float xv = __shfl(xx[rt], g * 4 + r);
            float dist = bd[rt][r] + xv;
            if (n == 0) lsum += dist;
        }
    __syncthreads();

    // ---- epilogue: gather q from ET (L2-hot), write coalesced. No x traffic.
#pragma unroll
    for (int p = 0; p < 2; ++p) {
        const int tok = p * 64 + (tid >> 2);
        const int part = tid & 3;
        const int gidx = idx_s[tok];
        const f32x4* ep = (const f32x4*)(ET + (size_t)gidx * D_DIM + part * 16);
        f32x4* qp = (f32x4*)(out_q + (size_t)(bt0 + tok) * D_DIM + part * 16);
#pragma unroll
        for (int u = 0; u < 4; ++u) qp[u] = ep[u];
    }

#pragma unroll
    for (int mask = 1; mask < 64; mask <<= 1) lsum += __shfl_xor(lsum, mask);
    if (l == 0) wsum_s[w] = lsum;
    __syncthreads();
    if (tid == 0) atomicAdd(out_loss, (wsum_s[0] + wsum_s[1] + wsum_s[2] + wsum_s[3]) * loss_scale);
}

// =================== round-1 fallback (proven) ===================
#define TOK_TILE 64
#define CHUNK 64
#define NCHUNK (K_CODES / CHUNK)
#define XS_STRIDE (TOK_TILE + 4)

__global__ __launch_bounds__(256, 4) void vq_fb_main(
        const float* __restrict__ x, const float* __restrict__ E,
        float* __restrict__ out_q, float* __restrict__ out_loss, float loss_scale) {
    __shared__ __align__(16) float Xs[D_DIM][XS_STRIDE];
    __shared__ __align__(16) float Es[D_DIM][CHUNK];
    __shared__ float ee_s[K_CODES];
    __shared__ int idx_s[TOK_TILE];
    __shared__ float wsum_s[4];

    const int tid = threadIdx.x;
    const int t0 = blockIdx.x * TOK_TILE;
    const int tx = tid & 15, ty = tid >> 4;
    const int ty4 = ty * 4, tx4 = tx * 4;

#pragma unroll
    for (int it = 0; it < 4; ++it) {
        int tl = it * 16 + (tid >> 4);
        int d0 = (tid & 15) * 4;
        float4 v = *(const float4*)(x + (size_t)(t0 + tl) * D_DIM + d0);
        Xs[d0 + 0][tl] = v.x; Xs[d0 + 1][tl] = v.y; Xs[d0 + 2][tl] = v.z; Xs[d0 + 3][tl] = v.w;
    }
    for (int k = tid; k < K_CODES; k += 256) {
        float s = 0.f;
#pragma unroll
        for (int d = 0; d < D_DIM; ++d) { float v = E[(size_t)d * K_CODES + k]; s = fmaf(v, v, s); }
        ee_s[k] = s;
    }

    float bd[4] = {3.4e38f, 3.4e38f, 3.4e38f, 3.4e38f};
    int bi[4] = {0, 0, 0, 0};

    for (int c = 0; c < NCHUNK; ++c) {
        __syncthreads();
#pragma unroll
        for (int ww = 0; ww < 4; ++ww) {
            int fidx = ww * 256 + tid;
            int d = fidx >> 4, k0 = (fidx & 15) * 4;
            float4 v = *(const float4*)(E + (size_t)d * K_CODES + c * CHUNK + k0);
            *(float4*)&Es[d][k0] = v;
        }
        __syncthreads();
        float acc[4][4] = {};
#pragma unroll
        for (int d = 0; d < D_DIM; ++d) {
            float4 a = *(const float4*)&Xs[d][ty4];
            float4 b = *(const float4*)&Es[d][tx4];
            acc[0][0] = fmaf(a.x, b.x, acc[0][0]); acc[0][1] = fmaf(a.x, b.y, acc[0][1]);
            acc[0][2] = fmaf(a.x, b.z, acc[0][2]); acc[0][3] = fmaf(a.x, b.w, acc[0][3]);
            acc[1][0] = fmaf(a.y, b.x, acc[1][0]); acc[1][1] = fmaf(a.y, b.y, acc[1][1]);
            acc[1][2] = fmaf(a.y, b.z, acc[1][2]); acc[1][3] = fmaf(a.y, b.w, acc[1][3]);
            acc[2][0] = fmaf(a.z, b.x, acc[2][0]); acc[2][1] = fmaf(a.z, b.y, acc[2][1]);
            acc[2][2] = fmaf(a.z, b.z, acc[2][2]); acc[2][3] = fmaf(a.z, b.w, acc[2][3]);
            acc[3][0] = fmaf(a.w, b.x, acc[3][0]); acc[3][1] = fmaf(a.w, b.y, acc[3][1]);
            acc[3][2] = fmaf(a.w, b.z, acc[3][2]); acc[3][3] = fmaf(a.w, b.w, acc[3][3]);
        }
        const int kbase = c * CHUNK + tx4;
#pragma unroll
        for (int i = 0; i < 4; ++i)
#pragma unroll
            for (int j = 0; j < 4; ++j) {
                float s = fmaf(-2.f, acc[i][j], ee_s[kbase + j]);
                if (s < bd[i]) { bd[i] = s; bi[i] = kbase + j; }
            }
    }
#pragma unroll
    for (int mask = 1; mask < 16; mask <<= 1)
#pragma unroll
        for (int i = 0; i < 4; ++i) {
            float od = __shfl_xor(bd[i], mask);
            int oi = __shfl_xor(bi[i], mask);
            if (od < bd[i] || (od == bd[i] && oi < bi[i])) { bd[i] = od; bi[i] = oi; }
        }
    if (tx == 0)
#pragma unroll
        for (int i = 0; i < 4; ++i) idx_s[ty4 + i] = bi[i];
    __syncthreads();

    const int tok = tid >> 2, part = tid & 3;
    const int gidx = idx_s[tok];
    const int gt = t0 + tok;
    float lsum = 0.f;
#pragma unroll
    for (int ww = 0; ww < 4; ++ww) {
        int o = part * 16 + ww * 4;
        float4 qv;
        qv.x = E[(size_t)(o + 0) * K_CODES + gidx];
        qv.y = E[(size_t)(o + 1) * K_CODES + gidx];
        qv.z = E[(size_t)(o + 2) * K_CODES + gidx];
        qv.w = E[(size_t)(o + 3) * K_CODES + gidx];
        float4 xv;
        xv.x = Xs[o + 0][tok]; xv.y = Xs[o + 1][tok]; xv.z = Xs[o + 2][tok]; xv.w = Xs[o + 3][tok];
        float dx = qv.x - xv.x, dy = qv.y - xv.y, dz = qv.z - xv.z, dw = qv.w - xv.w;
        lsum = fmaf(dx, dx, lsum); lsum = fmaf(dy, dy, lsum);
        lsum = fmaf(dz, dz, lsum); lsum = fmaf(dw, dw, lsum);
        *(float4*)(out_q + (size_t)gt * D_DIM + o) = qv;
    }
#pragma unroll
    for (int mask = 1; mask < 64; mask <<= 1) lsum += __shfl_xor(lsum, mask);
    if ((tid & 63) == 0) wsum_s[tid >> 6] = lsum;
    __syncthreads();
    if (tid == 0) atomicAdd(out_loss, (wsum_s[0] + wsum_s[1] + wsum_s[2] + wsum_s[3]) * loss_scale);
}

extern "C" void kernel_launch(void* const* d_in, const int* in_sizes, int n_in,
                              void* d_out, int out_size, void* d_ws, size_t ws_size,
                              hipStream_t stream) {
    const float* x = (const float*)d_in[0];   // [B,T,D] fp32
    const float* E = (const float*)d_in[1];   // [D,K] fp32
    float* out = (float*)d_out;
    const int n_tok = in_sizes[0] / D_DIM;    // 131072
    float* loss_ptr = out + (out_size - 1);
    const float loss_scale = 2.0f / (float)(n_tok * D_DIM);

    if (ws_size >= (size_t)WS_NEEDED) {
        float* ee = (float*)((char*)d_ws + WS_EE_OFF);
        float* ET = (float*)((char*)d_ws + WS_ET_OFF);
        _Float16* Bimg = (_Float16*)((char*)d_ws + WS_BIMG_OFF);
        vq3_prep<<<16, 256, 0, stream>>>(E, ee, ET, Bimg, loss_ptr);   // loss zeroed in prep
        vq3_main<<<n_tok / 128, 256, 0, stream>>>(x, ee, ET, Bimg, out, loss_ptr, loss_scale);
    } else {
        hipMemsetAsync(loss_ptr, 0, sizeof(float), stream);
        vq_fb_main<<<n_tok / TOK_TILE, 256, 0, stream>>>(x, E, out, loss_ptr, loss_scale);
    }
}

// Round 7
// 122.731 us; speedup vs baseline: 1.0258x; 1.0258x over previous
//
#include <hip/hip_runtime.h>
#include <hip/hip_bf16.h>

#define D_DIM 64
#define K_CODES 512

typedef _Float16 half8 __attribute__((ext_vector_type(8)));
typedef float f32x4 __attribute__((ext_vector_type(4)));

// ws layout: ee f32[512] @0 ; ET f32[512*64] @2048 B ; Bimg f16[512*64*2] @133120 B
#define WS_EE_OFF 0
#define WS_ET_OFF 2048
#define WS_BIMG_OFF 133120
#define WS_NEEDED (133120 + 131072)

// global_load_lds: wave-uniform LDS base + lane*16; per-lane global source.
#define GLDS16(gp, lp) __builtin_amdgcn_global_load_lds( \
    (const __attribute__((address_space(1))) unsigned int*)(gp), \
    (__attribute__((address_space(3))) unsigned int*)(lp), 16, 0, 0)

// ---------------- prep: ee, ET (gather layout), Bimg (frag-ordered f16 hi/lo of -2*E) ----
// (proven) thread u: code k = u>>3, dim-chunk dc = u&7. Coalesced half8/f32x4 stores;
// ee reduced over the 8 dc-lanes via shfl_xor. Zeroes the loss accumulator.
// Bimg holds the f16 split of (-2*E) (exact scaling), so the main kernel's MFMA
// accumulates ee - 2*x.e directly when hh is initialized with ee.
__global__ __launch_bounds__(256) void vq3_prep(const float* __restrict__ E,
                                                float* __restrict__ ee,
                                                float* __restrict__ ET,
                                                _Float16* __restrict__ Bimg,
                                                float* __restrict__ loss_ptr) {
    const int u = blockIdx.x * 256 + threadIdx.x;   // [0, 4096)
    if (u == 0) *loss_ptr = 0.f;
    const int k = u >> 3;          // code 0..511
    const int dc = u & 7;          // dim-chunk 0..7
    const int t = k >> 4, n = k & 15;
    const int ks = dc >> 2, g = dc & 3;

    float v[8];
    float s = 0.f;
    half8 hi, lo;
#pragma unroll
    for (int j = 0; j < 8; ++j) {
        float e = E[(size_t)(dc * 8 + j) * K_CODES + k];
        v[j] = e;
        s = fmaf(e, e, s);
        float em = -2.0f * e;                    // exact
        _Float16 h = (_Float16)em;
        hi[j] = h;
        lo[j] = (_Float16)((em - (float)h) * 2048.0f);
    }
    f32x4* etp = (f32x4*)(ET + (size_t)k * D_DIM + dc * 8);
    etp[0] = (f32x4){v[0], v[1], v[2], v[3]};
    etp[1] = (f32x4){v[4], v[5], v[6], v[7]};
    _Float16* bp = Bimg + (size_t)t * 2048 + g * 128 + n * 8;
    *(half8*)(bp + ks * 512) = hi;            // part = ks (hi)
    *(half8*)(bp + (2 + ks) * 512) = lo;      // part = 2+ks (lo, pre-scaled by 2^11)
    s += __shfl_xor(s, 1);
    s += __shfl_xor(s, 2);
    s += __shfl_xor(s, 4);
    if (dc == 0) ee[k] = s;
}

// ---------------- main: LDS-staged B + 4 waves/SIMD, 32 tokens/wave, grid 1024 -----------
// Rounds 5/6 post-mortem: with a 128-reg cap (launch_bounds(256,4) == waves_per_eu(4,4))
// the allocator lands one occupancy plateau BELOW the cap: 64 regs + ~16 loop spills
// (WRITE 33->57 MB of scratch). The only clean allocation (round 4) came from cap 256
// via waves_per_eu(2,2) -> allocator chose 128, zero spill. ONE change vs round 6:
// waves_per_eu(2,2). Demand ~80-100 regs << 128 -> no spill. HW occupancy is set by
// LDS+grid, not the attribute: 35.8 KB x 4 blocks/CU = 143 KB <= 160 KB, grid 1024 =
// 4 blocks/CU = 16 waves/CU = 4 waves/SIMD at <=128 VGPR (waves halve at 128).
//  * rt=2 (32 tokens/wave); LDS B double-buffer via global_load_lds, 1 barrier/chunk.
__attribute__((amdgpu_waves_per_eu(2, 2)))
__global__ __launch_bounds__(256) void vq3_main(
        const float* __restrict__ x, const float* __restrict__ ee,
        const float* __restrict__ ET, const _Float16* __restrict__ Bimg,
        float* __restrict__ out_q, float* __restrict__ out_loss, float loss_scale) {
    __shared__ __align__(16) _Float16 Bs[2][8192];   // 2 x 4 tiles x 2048 f16 = 32 KB
    __shared__ float ee_s[K_CODES];
    __shared__ int idx_s[128];
    __shared__ float wsum_s[4];

    const int tid = threadIdx.x;
    const int l = tid & 63;            // lane
    const int w = tid >> 6;            // wave in block
    const int g = l >> 4;              // k-group quad (0..3)
    const int n = l & 15;              // A row / B col within tile
    const int bt0 = blockIdx.x * 128;  // block token base
    const int t0 = bt0 + w * 32;       // wave token base (32 tokens/wave)

    // ---- issue chunk-0 staging FIRST (direct to LDS, latency hides under A-frag cvt)
    {
        const char* gsrc = (const char*)Bimg + w * 4096 + l * 16;
        char* ldst = (char*)&Bs[0][0] + w * 4096;          // wave-uniform
#pragma unroll
        for (int i = 0; i < 4; ++i) GLDS16(gsrc + i * 1024, ldst + i * 1024);
    }
    const float e0 = ee[tid], e1 = ee[tid + 256];

    // ---- A fragments: 2 row-tiles x 2 k-steps, hi and lo(x2^11), held in regs all kernel.
    // Also accumulate ||x||^2 per token (xx[rt], reduced over the 4 g-lane-groups).
    half8 Ahi[2][2], Alo[2][2];
    float xx[2];
#pragma unroll
    for (int rt = 0; rt < 2; ++rt) {
        float xs = 0.f;
#pragma unroll
        for (int ks = 0; ks < 2; ++ks) {
            const f32x4* xp = (const f32x4*)(x + (size_t)(t0 + rt * 16 + n) * D_DIM + ks * 32 + g * 8);
            f32x4 a = xp[0], b = xp[1];
            float va[8] = {a[0], a[1], a[2], a[3], b[0], b[1], b[2], b[3]};
            half8 h, lo;
#pragma unroll
            for (int j = 0; j < 8; ++j) {
                _Float16 hj = (_Float16)va[j];
                h[j] = hj;
                lo[j] = (_Float16)((va[j] - (float)hj) * 2048.0f);
                xs = fmaf(va[j], va[j], xs);
            }
            Ahi[rt][ks] = h;
            Alo[rt][ks] = lo;
        }
        xs += __shfl_xor(xs, 16);
        xs += __shfl_xor(xs, 32);
        xx[rt] = xs;
    }

    // ---- commit ee to LDS; barrier covers chunk-0 staging (vmcnt drain) + ee stores
    ee_s[tid] = e0;
    ee_s[tid + 256] = e1;
    __syncthreads();

    // ---- running argmin state (bd holds ee - 2*dot directly)
    float bd[2][4];
    int bi[2][4];
#pragma unroll
    for (int i = 0; i < 2; ++i)
#pragma unroll
        for (int r = 0; r < 4; ++r) { bd[i][r] = 3.4e38f; bi[i][r] = 0; }

    // ---- chunk loop: 8 chunks x 4 tiles; double-buffered LDS, 1 barrier/chunk.
    // Buffer (c+1)&1 was last READ in chunk c-1 (before the previous barrier), so the
    // staging writes issued at the top of chunk c cannot race any reader.
#pragma unroll 1
    for (int c = 0; c < 8; ++c) {
        if (c < 7) {
            const char* gsrc = (const char*)Bimg + (size_t)(c + 1) * 16384 + w * 4096 + l * 16;
            char* ldst = (char*)&Bs[(c + 1) & 1][0] + w * 4096;   // wave-uniform
#pragma unroll
            for (int i = 0; i < 4; ++i) GLDS16(gsrc + i * 1024, ldst + i * 1024);
        }
        const _Float16* bs = &Bs[c & 1][0];
#pragma unroll
        for (int tt = 0; tt < 4; ++tt) {
            const _Float16* tb = bs + tt * 2048 + l * 8;   // lane's 16B slot in each part
            half8 Bh0 = *(const half8*)(tb);
            half8 Bh1 = *(const half8*)(tb + 512);
            half8 Bl0 = *(const half8*)(tb + 1024);
            half8 Bl1 = *(const half8*)(tb + 1536);
            const int tg = c * 4 + tt;                     // global 16-code tile
            const float eev = ee_s[tg * 16 + n];           // broadcast within g-groups
            f32x4 hh[2], cr[2];
#pragma unroll
            for (int rt = 0; rt < 2; ++rt) {
                hh[rt] = (f32x4){eev, eev, eev, eev};      // accumulate ee - 2*dot directly
                cr[rt] = (f32x4){0.f, 0.f, 0.f, 0.f};
            }
#pragma unroll
            for (int rt = 0; rt < 2; ++rt) {
                hh[rt] = __builtin_amdgcn_mfma_f32_16x16x32_f16(Ahi[rt][0], Bh0, hh[rt], 0, 0, 0);
                hh[rt] = __builtin_amdgcn_mfma_f32_16x16x32_f16(Ahi[rt][1], Bh1, hh[rt], 0, 0, 0);
                cr[rt] = __builtin_amdgcn_mfma_f32_16x16x32_f16(Ahi[rt][0], Bl0, cr[rt], 0, 0, 0);
                cr[rt] = __builtin_amdgcn_mfma_f32_16x16x32_f16(Ahi[rt][1], Bl1, cr[rt], 0, 0, 0);
                cr[rt] = __builtin_amdgcn_mfma_f32_16x16x32_f16(Alo[rt][0], Bh0, cr[rt], 0, 0, 0);
                cr[rt] = __builtin_amdgcn_mfma_f32_16x16x32_f16(Alo[rt][1], Bh1, cr[rt], 0, 0, 0);
            }
            const int code = tg * 16 + n;
#pragma unroll
            for (int rt = 0; rt < 2; ++rt)
#pragma unroll
                for (int r = 0; r < 4; ++r) {
                    float s = fmaf(4.8828125e-4f, cr[rt][r], hh[rt][r]);  // hh + cross*2^-11
                    if (s < bd[rt][r]) { bd[rt][r] = s; bi[rt][r] = code; }
                }
        }
        __syncthreads();   // drains this chunk's staging (vmcnt) + all reads of bs
    }

    // ---- cross-lane argmin over the 16 code-columns (reduce over lane bits 0..3)
#pragma unroll
    for (int mask = 1; mask < 16; mask <<= 1) {
#pragma unroll
        for (int rt = 0; rt < 2; ++rt)
#pragma unroll
            for (int r = 0; r < 4; ++r) {
                float od = __shfl_xor(bd[rt][r], mask);
                int oi = __shfl_xor(bi[rt][r], mask);
                if (od < bd[rt][r] || (od == bd[rt][r] && oi < bi[rt][r])) { bd[rt][r] = od; bi[rt][r] = oi; }
            }
    }
    if (n == 0) {
#pragma unroll
        for (int rt = 0; rt < 2; ++rt)
#pragma unroll
            for (int r = 0; r < 4; ++r)
                idx_s[w * 32 + rt * 16 + g * 4 + r] = bi[rt][r];   // C-layout: row = g*4 + r
    }

    // ---- loss WITHOUT re-reading x: dist = bd_min + ||x||^2 (proven in round 2)
    float lsum = 0.f;
#pragma unroll
    for (int rt = 0; rt < 2; ++rt)
#pragma unroll
        for (int r = 0; r < 4; ++r) {
            float xv = __shfl(xx[rt], g * 4 + r);
            float dist = bd[rt][r] + xv;
            if (n == 0) lsum += dist;
        }
    __syncthreads();

    // ---- epilogue: gather q from ET (L2-hot), write coalesced. No x traffic.
#pragma unroll
    for (int p = 0; p < 2; ++p) {
        const int tok = p * 64 + (tid >> 2);
        const int part = tid & 3;
        const int gidx = idx_s[tok];
        const f32x4* ep = (const f32x4*)(ET + (size_t)gidx * D_DIM + part * 16);
        f32x4* qp = (f32x4*)(out_q + (size_t)(bt0 + tok) * D_DIM + part * 16);
#pragma unroll
        for (int u = 0; u < 4; ++u) qp[u] = ep[u];
    }

#pragma unroll
    for (int mask = 1; mask < 64; mask <<= 1) lsum += __shfl_xor(lsum, mask);
    if (l == 0) wsum_s[w] = lsum;
    __syncthreads();
    if (tid == 0) atomicAdd(out_loss, (wsum_s[0] + wsum_s[1] + wsum_s[2] + wsum_s[3]) * loss_scale);
}

// =================== round-1 fallback (proven) ===================
#define TOK_TILE 64
#define CHUNK 64
#define NCHUNK (K_CODES / CHUNK)
#define XS_STRIDE (TOK_TILE + 4)

__global__ __launch_bounds__(256, 4) void vq_fb_main(
        const float* __restrict__ x, const float* __restrict__ E,
        float* __restrict__ out_q, float* __restrict__ out_loss, float loss_scale) {
    __shared__ __align__(16) float Xs[D_DIM][XS_STRIDE];
    __shared__ __align__(16) float Es[D_DIM][CHUNK];
    __shared__ float ee_s[K_CODES];
    __shared__ int idx_s[TOK_TILE];
    __shared__ float wsum_s[4];

    const int tid = threadIdx.x;
    const int t0 = blockIdx.x * TOK_TILE;
    const int tx = tid & 15, ty = tid >> 4;
    const int ty4 = ty * 4, tx4 = tx * 4;

#pragma unroll
    for (int it = 0; it < 4; ++it) {
        int tl = it * 16 + (tid >> 4);
        int d0 = (tid & 15) * 4;
        float4 v = *(const float4*)(x + (size_t)(t0 + tl) * D_DIM + d0);
        Xs[d0 + 0][tl] = v.x; Xs[d0 + 1][tl] = v.y; Xs[d0 + 2][tl] = v.z; Xs[d0 + 3][tl] = v.w;
    }
    for (int k = tid; k < K_CODES; k += 256) {
        float s = 0.f;
#pragma unroll
        for (int d = 0; d < D_DIM; ++d) { float v = E[(size_t)d * K_CODES + k]; s = fmaf(v, v, s); }
        ee_s[k] = s;
    }

    float bd[4] = {3.4e38f, 3.4e38f, 3.4e38f, 3.4e38f};
    int bi[4] = {0, 0, 0, 0};

    for (int c = 0; c < NCHUNK; ++c) {
        __syncthreads();
#pragma unroll
        for (int ww = 0; ww < 4; ++ww) {
            int fidx = ww * 256 + tid;
            int d = fidx >> 4, k0 = (fidx & 15) * 4;
            float4 v = *(const float4*)(E + (size_t)d * K_CODES + c * CHUNK + k0);
            *(float4*)&Es[d][k0] = v;
        }
        __syncthreads();
        float acc[4][4] = {};
#pragma unroll
        for (int d = 0; d < D_DIM; ++d) {
            float4 a = *(const float4*)&Xs[d][ty4];
            float4 b = *(const float4*)&Es[d][tx4];
            acc[0][0] = fmaf(a.x, b.x, acc[0][0]); acc[0][1] = fmaf(a.x, b.y, acc[0][1]);
            acc[0][2] = fmaf(a.x, b.z, acc[0][2]); acc[0][3] = fmaf(a.x, b.w, acc[0][3]);
            acc[1][0] = fmaf(a.y, b.x, acc[1][0]); acc[1][1] = fmaf(a.y, b.y, acc[1][1]);
            acc[1][2] = fmaf(a.y, b.z, acc[1][2]); acc[1][3] = fmaf(a.y, b.w, acc[1][3]);
            acc[2][0] = fmaf(a.z, b.x, acc[2][0]); acc[2][1] = fmaf(a.z, b.y, acc[2][1]);
            acc[2][2] = fmaf(a.z, b.z, acc[2][2]); acc[2][3] = fmaf(a.z, b.w, acc[2][3]);
            acc[3][0] = fmaf(a.w, b.x, acc[3][0]); acc[3][1] = fmaf(a.w, b.y, acc[3][1]);
            acc[3][2] = fmaf(a.w, b.z, acc[3][2]); acc[3][3] = fmaf(a.w, b.w, acc[3][3]);
        }
        const int kbase = c * CHUNK + tx4;
#pragma unroll
        for (int i = 0; i < 4; ++i)
#pragma unroll
            for (int j = 0; j < 4; ++j) {
                float s = fmaf(-2.f, acc[i][j], ee_s[kbase + j]);
                if (s < bd[i]) { bd[i] = s; bi[i] = kbase + j; }
            }
    }
#pragma unroll
    for (int mask = 1; mask < 16; mask <<= 1)
#pragma unroll
        for (int i = 0; i < 4; ++i) {
            float od = __shfl_xor(bd[i], mask);
            int oi = __shfl_xor(bi[i], mask);
            if (od < bd[i] || (od == bd[i] && oi < bi[i])) { bd[i] = od; bi[i] = oi; }
        }
    if (tx == 0)
#pragma unroll
        for (int i = 0; i < 4; ++i) idx_s[ty4 + i] = bi[i];
    __syncthreads();

    const int tok = tid >> 2, part = tid & 3;
    const int gidx = idx_s[tok];
    const int gt = t0 + tok;
    float lsum = 0.f;
#pragma unroll
    for (int ww = 0; ww < 4; ++ww) {
        int o = part * 16 + ww * 4;
        float4 qv;
        qv.x = E[(size_t)(o + 0) * K_CODES + gidx];
        qv.y = E[(size_t)(o + 1) * K_CODES + gidx];
        qv.z = E[(size_t)(o + 2) * K_CODES + gidx];
        qv.w = E[(size_t)(o + 3) * K_CODES + gidx];
        float4 xv;
        xv.x = Xs[o + 0][tok]; xv.y = Xs[o + 1][tok]; xv.z = Xs[o + 2][tok]; xv.w = Xs[o + 3][tok];
        float dx = qv.x - xv.x, dy = qv.y - xv.y, dz = qv.z - xv.z, dw = qv.w - xv.w;
        lsum = fmaf(dx, dx, lsum); lsum = fmaf(dy, dy, lsum);
        lsum = fmaf(dz, dz, lsum); lsum = fmaf(dw, dw, lsum);
        *(float4*)(out_q + (size_t)gt * D_DIM + o) = qv;
    }
#pragma unroll
    for (int mask = 1; mask < 64; mask <<= 1) lsum += __shfl_xor(lsum, mask);
    if ((tid & 63) == 0) wsum_s[tid >> 6] = lsum;
    __syncthreads();
    if (tid == 0) atomicAdd(out_loss, (wsum_s[0] + wsum_s[1] + wsum_s[2] + wsum_s[3]) * loss_scale);
}

extern "C" void kernel_launch(void* const* d_in, const int* in_sizes, int n_in,
                              void* d_out, int out_size, void* d_ws, size_t ws_size,
                              hipStream_t stream) {
    const float* x = (const float*)d_in[0];   // [B,T,D] fp32
    const float* E = (const float*)d_in[1];   // [D,K] fp32
    float* out = (float*)d_out;
    const int n_tok = in_sizes[0] / D_DIM;    // 131072
    float* loss_ptr = out + (out_size - 1);
    const float loss_scale = 2.0f / (float)(n_tok * D_DIM);

    if (ws_size >= (size_t)WS_NEEDED) {
        float* ee = (float*)((char*)d_ws + WS_EE_OFF);
        float* ET = (float*)((char*)d_ws + WS_ET_OFF);
        _Float16* Bimg = (_Float16*)((char*)d_ws + WS_BIMG_OFF);
        vq3_prep<<<16, 256, 0, stream>>>(E, ee, ET, Bimg, loss_ptr);   // loss zeroed in prep
        vq3_main<<<n_tok / 128, 256, 0, stream>>>(x, ee, ET, Bimg, out, loss_ptr, loss_scale);
    } else {
        hipMemsetAsync(loss_ptr, 0, sizeof(float), stream);
        vq_fb_main<<<n_tok / TOK_TILE, 256, 0, stream>>>(x, E, out, loss_ptr, loss_scale);
    }
}

// Round 9
// 122.225 us; speedup vs baseline: 1.0301x; 1.0041x over previous
//
#include <hip/hip_runtime.h>
#include <hip/hip_bf16.h>

#define D_DIM 64
#define K_CODES 512

typedef _Float16 half8 __attribute__((ext_vector_type(8)));
typedef float f32x4 __attribute__((ext_vector_type(4)));

// ws layout: ee f32[512] @0 ; ET f32[512*64] @2048 B ; Bimg f16[512*64*2] @133120 B
#define WS_EE_OFF 0
#define WS_ET_OFF 2048
#define WS_BIMG_OFF 133120
#define WS_NEEDED (133120 + 131072)

// global_load_lds: wave-uniform LDS base + lane*16; per-lane global source.
#define GLDS16(gp, lp) __builtin_amdgcn_global_load_lds( \
    (const __attribute__((address_space(1))) unsigned int*)(gp), \
    (__attribute__((address_space(3))) unsigned int*)(lp), 16, 0, 0)

// ---------------- prep: ee, ET (gather layout), Bimg (frag-ordered f16 hi/lo of -2*E) ----
// (proven) thread u: code k = u>>3, dim-chunk dc = u&7. Coalesced half8/f32x4 stores;
// ee reduced over the 8 dc-lanes via shfl_xor. Zeroes the loss accumulator.
// Bimg holds the f16 split of (-2*E) (exact scaling), so the main kernel's MFMA
// accumulates ee - 2*x.e directly when hh is initialized with ee.
__global__ __launch_bounds__(256) void vq3_prep(const float* __restrict__ E,
                                                float* __restrict__ ee,
                                                float* __restrict__ ET,
                                                _Float16* __restrict__ Bimg,
                                                float* __restrict__ loss_ptr) {
    const int u = blockIdx.x * 256 + threadIdx.x;   // [0, 4096)
    if (u == 0) *loss_ptr = 0.f;
    const int k = u >> 3;          // code 0..511
    const int dc = u & 7;          // dim-chunk 0..7
    const int t = k >> 4, n = k & 15;
    const int ks = dc >> 2, g = dc & 3;

    float v[8];
    float s = 0.f;
    half8 hi, lo;
#pragma unroll
    for (int j = 0; j < 8; ++j) {
        float e = E[(size_t)(dc * 8 + j) * K_CODES + k];
        v[j] = e;
        s = fmaf(e, e, s);
        float em = -2.0f * e;                    // exact
        _Float16 h = (_Float16)em;
        hi[j] = h;
        lo[j] = (_Float16)((em - (float)h) * 2048.0f);
    }
    f32x4* etp = (f32x4*)(ET + (size_t)k * D_DIM + dc * 8);
    etp[0] = (f32x4){v[0], v[1], v[2], v[3]};
    etp[1] = (f32x4){v[4], v[5], v[6], v[7]};
    _Float16* bp = Bimg + (size_t)t * 2048 + g * 128 + n * 8;
    *(half8*)(bp + ks * 512) = hi;            // part = ks (hi)
    *(half8*)(bp + (2 + ks) * 512) = lo;      // part = 2+ks (lo, pre-scaled by 2^11)
    s += __shfl_xor(s, 1);
    s += __shfl_xor(s, 2);
    s += __shfl_xor(s, 4);
    if (dc == 0) ee[k] = s;
}

// ---------------- main: LDS-staged B, rt=4, 2-WAVE BLOCKS, 4 blocks/CU, grid 1024 --------
// (Resubmission of round 8 -- container infra failure, hypothesis untested.)
// Round-7 post-mortem: rt=2 doubled per-CU LDS B-read traffic (waves-sharing x 128 KB) and
// regressed 48.5->55.4us -- the loop's largest consumer is LDS read BW, so rt=4 (round 4)
// is the right tile. Cycle model at 770 MHz effective clock: MFMA 7.4k + VALU 9k + LDS
// ~13k ~= measured 37k total => pipes are SERIALIZED, not overlapped. This round keeps
// round-4's per-wave code exactly (VGPR 128, clean) and changes only scheduling structure:
//  * 128-thread (2-wave) blocks, grid 1024 = 4 blocks/CU = 8 waves/CU.
//  * 4 independent barrier domains per CU: barriers sync 2 waves only, and the 4 blocks'
//    prologue/loop/epilogue phases stagger, filling each other's stalls.
//  * LDS 34.6 KB/block x 4 = 138 KB <= 160 KB. Staging L2 traffic doubles (512 KB/CU) --
//    cheap next to the stall it hides.
//  * waves_per_eu(2,2): budget 1024 regs -> allocator unconstrained, picks natural ~128
//    (proven round 4/7: clean, no spill). Any allocation <=256 keeps 2 waves/SIMD.
__attribute__((amdgpu_waves_per_eu(2, 2)))
__global__ __launch_bounds__(128) void vq3_main(
        const float* __restrict__ x, const float* __restrict__ ee,
        const float* __restrict__ ET, const _Float16* __restrict__ Bimg,
        float* __restrict__ out_q, float* __restrict__ out_loss, float loss_scale) {
    __shared__ __align__(16) _Float16 Bs[2][8192];   // 2 x 4 tiles x 2048 f16 = 32 KB
    __shared__ float ee_s[K_CODES];
    __shared__ int idx_s[128];
    __shared__ float wsum_s[2];

    const int tid = threadIdx.x;       // 0..127
    const int l = tid & 63;            // lane
    const int w = tid >> 6;            // wave in block (0..1)
    const int g = l >> 4;              // k-group quad (0..3)
    const int n = l & 15;              // A row / B col within tile
    const int bt0 = blockIdx.x * 128;  // block token base
    const int t0 = bt0 + w * 64;       // wave token base (64 tokens/wave)

    // ---- issue chunk-0 staging FIRST (direct to LDS, latency hides under A-frag cvt).
    // Wave w stages its 8 KB half of the 16 KB chunk: 8 x 1 KB GLDS.
    {
        const char* gsrc = (const char*)Bimg + w * 8192 + l * 16;
        char* ldst = (char*)&Bs[0][0] + w * 8192;          // wave-uniform
#pragma unroll
        for (int i = 0; i < 8; ++i) GLDS16(gsrc + i * 1024, ldst + i * 1024);
    }
    float ev[4];
#pragma unroll
    for (int i = 0; i < 4; ++i) ev[i] = ee[tid + i * 128];

    // ---- A fragments: 4 row-tiles x 2 k-steps, hi and lo(x2^11), held in regs all kernel.
    // Also accumulate ||x||^2 per token (xx[rt], reduced over the 4 g-lane-groups).
    half8 Ahi[4][2], Alo[4][2];
    float xx[4];
#pragma unroll
    for (int rt = 0; rt < 4; ++rt) {
        float xs = 0.f;
#pragma unroll
        for (int ks = 0; ks < 2; ++ks) {
            const f32x4* xp = (const f32x4*)(x + (size_t)(t0 + rt * 16 + n) * D_DIM + ks * 32 + g * 8);
            f32x4 a = xp[0], b = xp[1];
            float va[8] = {a[0], a[1], a[2], a[3], b[0], b[1], b[2], b[3]};
            half8 h, lo;
#pragma unroll
            for (int j = 0; j < 8; ++j) {
                _Float16 hj = (_Float16)va[j];
                h[j] = hj;
                lo[j] = (_Float16)((va[j] - (float)hj) * 2048.0f);
                xs = fmaf(va[j], va[j], xs);
            }
            Ahi[rt][ks] = h;
            Alo[rt][ks] = lo;
        }
        xs += __shfl_xor(xs, 16);
        xs += __shfl_xor(xs, 32);
        xx[rt] = xs;
    }

    // ---- commit ee to LDS; barrier covers chunk-0 staging (vmcnt drain) + ee stores
#pragma unroll
    for (int i = 0; i < 4; ++i) ee_s[tid + i * 128] = ev[i];
    __syncthreads();

    // ---- running argmin state (bd holds ee - 2*dot directly)
    float bd[4][4];
    int bi[4][4];
#pragma unroll
    for (int i = 0; i < 4; ++i)
#pragma unroll
        for (int r = 0; r < 4; ++r) { bd[i][r] = 3.4e38f; bi[i][r] = 0; }

    // ---- chunk loop: 8 chunks x 4 tiles; double-buffered LDS, 1 (2-wave) barrier/chunk.
    // Buffer (c+1)&1 was last READ in chunk c-1 (before the previous barrier), so the
    // staging writes issued at the top of chunk c cannot race any reader.
#pragma unroll 2
    for (int c = 0; c < 8; ++c) {
        if (c < 7) {
            const char* gsrc = (const char*)Bimg + (size_t)(c + 1) * 16384 + w * 8192 + l * 16;
            char* ldst = (char*)&Bs[(c + 1) & 1][0] + w * 8192;   // wave-uniform
#pragma unroll
            for (int i = 0; i < 8; ++i) GLDS16(gsrc + i * 1024, ldst + i * 1024);
        }
        const _Float16* bs = &Bs[c & 1][0];
#pragma unroll
        for (int tt = 0; tt < 4; ++tt) {
            const _Float16* tb = bs + tt * 2048 + l * 8;   // lane's 16B slot in each part
            half8 Bh0 = *(const half8*)(tb);
            half8 Bh1 = *(const half8*)(tb + 512);
            half8 Bl0 = *(const half8*)(tb + 1024);
            half8 Bl1 = *(const half8*)(tb + 1536);
            const int tg = c * 4 + tt;                     // global 16-code tile
            const float eev = ee_s[tg * 16 + n];           // broadcast within g-groups
            f32x4 hh[4], cr[4];
#pragma unroll
            for (int rt = 0; rt < 4; ++rt) {
                hh[rt] = (f32x4){eev, eev, eev, eev};      // accumulate ee - 2*dot directly
                cr[rt] = (f32x4){0.f, 0.f, 0.f, 0.f};
            }
#pragma unroll
            for (int rt = 0; rt < 4; ++rt) {
                hh[rt] = __builtin_amdgcn_mfma_f32_16x16x32_f16(Ahi[rt][0], Bh0, hh[rt], 0, 0, 0);
                hh[rt] = __builtin_amdgcn_mfma_f32_16x16x32_f16(Ahi[rt][1], Bh1, hh[rt], 0, 0, 0);
                cr[rt] = __builtin_amdgcn_mfma_f32_16x16x32_f16(Ahi[rt][0], Bl0, cr[rt], 0, 0, 0);
                cr[rt] = __builtin_amdgcn_mfma_f32_16x16x32_f16(Ahi[rt][1], Bl1, cr[rt], 0, 0, 0);
                cr[rt] = __builtin_amdgcn_mfma_f32_16x16x32_f16(Alo[rt][0], Bh0, cr[rt], 0, 0, 0);
                cr[rt] = __builtin_amdgcn_mfma_f32_16x16x32_f16(Alo[rt][1], Bh1, cr[rt], 0, 0, 0);
            }
            const int code = tg * 16 + n;
#pragma unroll
            for (int rt = 0; rt < 4; ++rt)
#pragma unroll
                for (int r = 0; r < 4; ++r) {
                    float s = fmaf(4.8828125e-4f, cr[rt][r], hh[rt][r]);  // hh + cross*2^-11
                    if (s < bd[rt][r]) { bd[rt][r] = s; bi[rt][r] = code; }
                }
        }
        __syncthreads();   // drains this chunk's staging (vmcnt) + all reads of bs
    }

    // ---- cross-lane argmin over the 16 code-columns (reduce over lane bits 0..3)
#pragma unroll
    for (int mask = 1; mask < 16; mask <<= 1) {
#pragma unroll
        for (int rt = 0; rt < 4; ++rt)
#pragma unroll
            for (int r = 0; r < 4; ++r) {
                float od = __shfl_xor(bd[rt][r], mask);
                int oi = __shfl_xor(bi[rt][r], mask);
                if (od < bd[rt][r] || (od == bd[rt][r] && oi < bi[rt][r])) { bd[rt][r] = od; bi[rt][r] = oi; }
            }
    }
    if (n == 0) {
#pragma unroll
        for (int rt = 0; rt < 4; ++rt)
#pragma unroll
            for (int r = 0; r < 4; ++r)
                idx_s[w * 64 + rt * 16 + g * 4 + r] = bi[rt][r];   // C-layout: row = g*4 + r
    }

    // ---- loss WITHOUT re-reading x: dist = bd_min + ||x||^2 (proven in round 2)
    float lsum = 0.f;
#pragma unroll
    for (int rt = 0; rt < 4; ++rt)
#pragma unroll
        for (int r = 0; r < 4; ++r) {
            float xv = __shfl(xx[rt], g * 4 + r);
            float dist = bd[rt][r] + xv;
            if (n == 0) lsum += dist;
        }
    __syncthreads();

    // ---- epilogue: gather q from ET (L2-hot), write coalesced. No x traffic.
    // 128 threads, 128 tokens: per p, 32 tokens x 4 parts.
#pragma unroll
    for (int p = 0; p < 4; ++p) {
        const int tok = p * 32 + (tid >> 2);
        const int part = tid & 3;
        const int gidx = idx_s[tok];
        const f32x4* ep = (const f32x4*)(ET + (size_t)gidx * D_DIM + part * 16);
        f32x4* qp = (f32x4*)(out_q + (size_t)(bt0 + tok) * D_DIM + part * 16);
#pragma unroll
        for (int u = 0; u < 4; ++u) qp[u] = ep[u];
    }

#pragma unroll
    for (int mask = 1; mask < 64; mask <<= 1) lsum += __shfl_xor(lsum, mask);
    if (l == 0) wsum_s[w] = lsum;
    __syncthreads();
    if (tid == 0) atomicAdd(out_loss, (wsum_s[0] + wsum_s[1]) * loss_scale);
}

// =================== round-1 fallback (proven) ===================
#define TOK_TILE 64
#define CHUNK 64
#define NCHUNK (K_CODES / CHUNK)
#define XS_STRIDE (TOK_TILE + 4)

__global__ __launch_bounds__(256, 4) void vq_fb_main(
        const float* __restrict__ x, const float* __restrict__ E,
        float* __restrict__ out_q, float* __restrict__ out_loss, float loss_scale) {
    __shared__ __align__(16) float Xs[D_DIM][XS_STRIDE];
    __shared__ __align__(16) float Es[D_DIM][CHUNK];
    __shared__ float ee_s[K_CODES];
    __shared__ int idx_s[TOK_TILE];
    __shared__ float wsum_s[4];

    const int tid = threadIdx.x;
    const int t0 = blockIdx.x * TOK_TILE;
    const int tx = tid & 15, ty = tid >> 4;
    const int ty4 = ty * 4, tx4 = tx * 4;

#pragma unroll
    for (int it = 0; it < 4; ++it) {
        int tl = it * 16 + (tid >> 4);
        int d0 = (tid & 15) * 4;
        float4 v = *(const float4*)(x + (size_t)(t0 + tl) * D_DIM + d0);
        Xs[d0 + 0][tl] = v.x; Xs[d0 + 1][tl] = v.y; Xs[d0 + 2][tl] = v.z; Xs[d0 + 3][tl] = v.w;
    }
    for (int k = tid; k < K_CODES; k += 256) {
        float s = 0.f;
#pragma unroll
        for (int d = 0; d < D_DIM; ++d) { float v = E[(size_t)d * K_CODES + k]; s = fmaf(v, v, s); }
        ee_s[k] = s;
    }

    float bd[4] = {3.4e38f, 3.4e38f, 3.4e38f, 3.4e38f};
    int bi[4] = {0, 0, 0, 0};

    for (int c = 0; c < NCHUNK; ++c) {
        __syncthreads();
#pragma unroll
        for (int ww = 0; ww < 4; ++ww) {
            int fidx = ww * 256 + tid;
            int d = fidx >> 4, k0 = (fidx & 15) * 4;
            float4 v = *(const float4*)(E + (size_t)d * K_CODES + c * CHUNK + k0);
            *(float4*)&Es[d][k0] = v;
        }
        __syncthreads();
        float acc[4][4] = {};
#pragma unroll
        for (int d = 0; d < D_DIM; ++d) {
            float4 a = *(const float4*)&Xs[d][ty4];
            float4 b = *(const float4*)&Es[d][tx4];
            acc[0][0] = fmaf(a.x, b.x, acc[0][0]); acc[0][1] = fmaf(a.x, b.y, acc[0][1]);
            acc[0][2] = fmaf(a.x, b.z, acc[0][2]); acc[0][3] = fmaf(a.x, b.w, acc[0][3]);
            acc[1][0] = fmaf(a.y, b.x, acc[1][0]); acc[1][1] = fmaf(a.y, b.y, acc[1][1]);
            acc[1][2] = fmaf(a.y, b.z, acc[1][2]); acc[1][3] = fmaf(a.y, b.w, acc[1][3]);
            acc[2][0] = fmaf(a.z, b.x, acc[2][0]); acc[2][1] = fmaf(a.z, b.y, acc[2][1]);
            acc[2][2] = fmaf(a.z, b.z, acc[2][2]); acc[2][3] = fmaf(a.z, b.w, acc[2][3]);
            acc[3][0] = fmaf(a.w, b.x, acc[3][0]); acc[3][1] = fmaf(a.w, b.y, acc[3][1]);
            acc[3][2] = fmaf(a.w, b.z, acc[3][2]); acc[3][3] = fmaf(a.w, b.w, acc[3][3]);
        }
        const int kbase = c * CHUNK + tx4;
#pragma unroll
        for (int i = 0; i < 4; ++i)
#pragma unroll
            for (int j = 0; j < 4; ++j) {
                float s = fmaf(-2.f, acc[i][j], ee_s[kbase + j]);
                if (s < bd[i]) { bd[i] = s; bi[i] = kbase + j; }
            }
    }
#pragma unroll
    for (int mask = 1; mask < 16; mask <<= 1)
#pragma unroll
        for (int i = 0; i < 4; ++i) {
            float od = __shfl_xor(bd[i], mask);
            int oi = __shfl_xor(bi[i], mask);
            if (od < bd[i] || (od == bd[i] && oi < bi[i])) { bd[i] = od; bi[i] = oi; }
        }
    if (tx == 0)
#pragma unroll
        for (int i = 0; i < 4; ++i) idx_s[ty4 + i] = bi[i];
    __syncthreads();

    const int tok = tid >> 2, part = tid & 3;
    const int gidx = idx_s[tok];
    const int gt = t0 + tok;
    float lsum = 0.f;
#pragma unroll
    for (int ww = 0; ww < 4; ++ww) {
        int o = part * 16 + ww * 4;
        float4 qv;
        qv.x = E[(size_t)(o + 0) * K_CODES + gidx];
        qv.y = E[(size_t)(o + 1) * K_CODES + gidx];
        qv.z = E[(size_t)(o + 2) * K_CODES + gidx];
        qv.w = E[(size_t)(o + 3) * K_CODES + gidx];
        float4 xv;
        xv.x = Xs[o + 0][tok]; xv.y = Xs[o + 1][tok]; xv.z = Xs[o + 2][tok]; xv.w = Xs[o + 3][tok];
        float dx = qv.x - xv.x, dy = qv.y - xv.y, dz = qv.z - xv.z, dw = qv.w - xv.w;
        lsum = fmaf(dx, dx, lsum); lsum = fmaf(dy, dy, lsum);
        lsum = fmaf(dz, dz, lsum); lsum = fmaf(dw, dw, lsum);
        *(float4*)(out_q + (size_t)gt * D_DIM + o) = qv;
    }
#pragma unroll
    for (int mask = 1; mask < 64; mask <<= 1) lsum += __shfl_xor(lsum, mask);
    if ((tid & 63) == 0) wsum_s[tid >> 6] = lsum;
    __syncthreads();
    if (tid == 0) atomicAdd(out_loss, (wsum_s[0] + wsum_s[1] + wsum_s[2] + wsum_s[3]) * loss_scale);
}

extern "C" void kernel_launch(void* const* d_in, const int* in_sizes, int n_in,
                              void* d_out, int out_size, void* d_ws, size_t ws_size,
                              hipStream_t stream) {
    const float* x = (const float*)d_in[0];   // [B,T,D] fp32
    const float* E = (const float*)d_in[1];   // [D,K] fp32
    float* out = (float*)d_out;
    const int n_tok = in_sizes[0] / D_DIM;    // 131072
    float* loss_ptr = out + (out_size - 1);
    const float loss_scale = 2.0f / (float)(n_tok * D_DIM);

    if (ws_size >= (size_t)WS_NEEDED) {
        float* ee = (float*)((char*)d_ws + WS_EE_OFF);
        float* ET = (float*)((char*)d_ws + WS_ET_OFF);
        _Float16* Bimg = (_Float16*)((char*)d_ws + WS_BIMG_OFF);
        vq3_prep<<<16, 256, 0, stream>>>(E, ee, ET, Bimg, loss_ptr);   // loss zeroed in prep
        vq3_main<<<n_tok / 128, 128, 0, stream>>>(x, ee, ET, Bimg, out, loss_ptr, loss_scale);
    } else {
        hipMemsetAsync(loss_ptr, 0, sizeof(float), stream);
        vq_fb_main<<<n_tok / TOK_TILE, 256, 0, stream>>>(x, E, out, loss_ptr, loss_scale);
    }
}

// Round 10
// 115.210 us; speedup vs baseline: 1.0928x; 1.0609x over previous
//
#include <hip/hip_runtime.h>
#include <hip/hip_bf16.h>

#define D_DIM 64
#define K_CODES 512

typedef _Float16 half8 __attribute__((ext_vector_type(8)));
typedef float f32x4 __attribute__((ext_vector_type(4)));

// ws layout: ee f32[512] @0 ; ET f32[512*64] @2048 B ; Bimg f16[512*64*2] @133120 B
#define WS_EE_OFF 0
#define WS_ET_OFF 2048
#define WS_BIMG_OFF 133120
#define WS_NEEDED (133120 + 131072)

// ---------------- prep: ee, ET (gather layout), Bimg (frag-ordered f16 hi/lo of -2*E) ----
// (proven) thread u: code k = u>>3, dim-chunk dc = u&7. Coalesced half8/f32x4 stores;
// ee reduced over the 8 dc-lanes via shfl_xor. Zeroes the loss accumulator.
// Bimg holds the f16 split of (-2*E) (exact scaling), so the main kernel's MFMA
// accumulates ee - 2*x.e directly when hh is initialized with ee.
__global__ __launch_bounds__(256) void vq3_prep(const float* __restrict__ E,
                                                float* __restrict__ ee,
                                                float* __restrict__ ET,
                                                _Float16* __restrict__ Bimg,
                                                float* __restrict__ loss_ptr) {
    const int u = blockIdx.x * 256 + threadIdx.x;   // [0, 4096)
    if (u == 0) *loss_ptr = 0.f;
    const int k = u >> 3;          // code 0..511
    const int dc = u & 7;          // dim-chunk 0..7
    const int t = k >> 4, n = k & 15;
    const int ks = dc >> 2, g = dc & 3;

    float v[8];
    float s = 0.f;
    half8 hi, lo;
#pragma unroll
    for (int j = 0; j < 8; ++j) {
        float e = E[(size_t)(dc * 8 + j) * K_CODES + k];
        v[j] = e;
        s = fmaf(e, e, s);
        float em = -2.0f * e;                    // exact
        _Float16 h = (_Float16)em;
        hi[j] = h;
        lo[j] = (_Float16)((em - (float)h) * 2048.0f);
    }
    f32x4* etp = (f32x4*)(ET + (size_t)k * D_DIM + dc * 8);
    etp[0] = (f32x4){v[0], v[1], v[2], v[3]};
    etp[1] = (f32x4){v[4], v[5], v[6], v[7]};
    _Float16* bp = Bimg + (size_t)t * 2048 + g * 128 + n * 8;
    *(half8*)(bp + ks * 512) = hi;            // part = ks (hi)
    *(half8*)(bp + (2 + ks) * 512) = lo;      // part = 2+ks (lo, pre-scaled by 2^11)
    s += __shfl_xor(s, 1);
    s += __shfl_xor(s, 2);
    s += __shfl_xor(s, 4);
    if (dc == 0) ee[k] = s;
}

// ---------------- main: BARRIER-FREE loop, reg-prefetched B (3-slot, 2-deep), rt=4 -------
// Round-9 post-mortem: all structural variants (8 vs 16 waves/CU, 2- vs 4-wave barrier
// domains, LDS vs global B) land 50+-4us ~= 42k cyc; busy work is only ~20k cyc => ~21k
// cyc is all-waves-stalled time around lgkmcnt/vmcnt + the per-chunk barrier drain. The
// one thing never tried: NO BARRIERS in the loop. This round drops LDS staging of B
// entirely and prefetches B-fragments into a 3-slot register ring (2 compute bodies ~=
// 650 cyc of slack per slot > L2 latency). Compiler emits COUNTED vmcnt before each
// slot's first use (full drains only happen before s_barrier -- none here).
//  * grid 512 x 256 thr, rt=4 (64 tok/wave), 2 blocks/CU, 2 waves/SIMD (grid-limited).
//  * ee in LDS (2 KB, read-only after prologue); B L2 traffic 1 MB/CU ~ 1.1 TB/s/XCD.
//  * VGPR demand ~166; waves_per_eu(2,2) allocates demand (r4/r7/r9 proven), no spill.
//  * Tile schedule: prologue loads 0,1; body t: {load t+2, comp t}{load t+3, comp t+1}
//    {load t+4, comp t+2} for t=0..27 step 3; tail computes 30,31. Each tile exactly once.
__attribute__((amdgpu_waves_per_eu(2, 2)))
__global__ __launch_bounds__(256) void vq3_main(
        const float* __restrict__ x, const float* __restrict__ ee,
        const float* __restrict__ ET, const _Float16* __restrict__ Bimg,
        float* __restrict__ out_q, float* __restrict__ out_loss, float loss_scale) {
    __shared__ float ee_s[K_CODES];
    __shared__ int idx_s[256];
    __shared__ float wsum_s[4];

    const int tid = threadIdx.x;
    const int l = tid & 63;            // lane
    const int w = tid >> 6;            // wave in block (0..3)
    const int g = l >> 4;              // k-group quad (0..3)
    const int n = l & 15;              // A row / B col within tile
    const int bt0 = blockIdx.x * 256;  // block token base
    const int t0 = bt0 + w * 64;       // wave token base (64 tokens/wave)

    // ---- ee loads issued first (latency hides under A-frag cvt)
    const float e0 = ee[tid], e1 = ee[tid + 256];

    // ---- A fragments: 4 row-tiles x 2 k-steps, hi and lo(x2^11), held in regs all kernel.
    // Also accumulate ||x||^2 per token (xx[rt], reduced over the 4 g-lane-groups).
    half8 Ahi[4][2], Alo[4][2];
    float xx[4];
#pragma unroll
    for (int rt = 0; rt < 4; ++rt) {
        float xs = 0.f;
#pragma unroll
        for (int ks = 0; ks < 2; ++ks) {
            const f32x4* xp = (const f32x4*)(x + (size_t)(t0 + rt * 16 + n) * D_DIM + ks * 32 + g * 8);
            f32x4 a = xp[0], b = xp[1];
            float va[8] = {a[0], a[1], a[2], a[3], b[0], b[1], b[2], b[3]};
            half8 h, lo;
#pragma unroll
            for (int j = 0; j < 8; ++j) {
                _Float16 hj = (_Float16)va[j];
                h[j] = hj;
                lo[j] = (_Float16)((va[j] - (float)hj) * 2048.0f);
                xs = fmaf(va[j], va[j], xs);
            }
            Ahi[rt][ks] = h;
            Alo[rt][ks] = lo;
        }
        xs += __shfl_xor(xs, 16);
        xs += __shfl_xor(xs, 32);
        xx[rt] = xs;
    }

    // ---- commit ee to LDS; the ONLY pre-loop barrier (ee_s is read-only afterwards)
    ee_s[tid] = e0;
    ee_s[tid + 256] = e1;
    __syncthreads();

    // ---- running argmin state (bd holds ee - 2*dot directly)
    float bd[4][4];
    int bi[4][4];
#pragma unroll
    for (int i = 0; i < 4; ++i)
#pragma unroll
        for (int r = 0; r < 4; ++r) { bd[i][r] = 3.4e38f; bi[i][r] = 0; }

    const _Float16* bbase = Bimg + (size_t)g * 128 + n * 8;

#define DECL_SLOT(S) half8 S##h0, S##h1, S##l0, S##l1;
    DECL_SLOT(s0) DECL_SLOT(s1) DECL_SLOT(s2)

#define LOAD_SLOT(S, tile) { \
    const _Float16* bp_ = bbase + (size_t)(tile) * 2048; \
    S##h0 = *(const half8*)(bp_); \
    S##h1 = *(const half8*)(bp_ + 512); \
    S##l0 = *(const half8*)(bp_ + 1024); \
    S##l1 = *(const half8*)(bp_ + 1536); }

#define COMP_SLOT(S, tile) { \
    const float eev = ee_s[(tile) * 16 + n]; \
    f32x4 hh[4], cr[4]; \
    _Pragma("unroll") \
    for (int rt = 0; rt < 4; ++rt) { \
        hh[rt] = (f32x4){eev, eev, eev, eev}; \
        cr[rt] = (f32x4){0.f, 0.f, 0.f, 0.f}; \
    } \
    _Pragma("unroll") \
    for (int rt = 0; rt < 4; ++rt) { \
        hh[rt] = __builtin_amdgcn_mfma_f32_16x16x32_f16(Ahi[rt][0], S##h0, hh[rt], 0, 0, 0); \
        hh[rt] = __builtin_amdgcn_mfma_f32_16x16x32_f16(Ahi[rt][1], S##h1, hh[rt], 0, 0, 0); \
        cr[rt] = __builtin_amdgcn_mfma_f32_16x16x32_f16(Ahi[rt][0], S##l0, cr[rt], 0, 0, 0); \
        cr[rt] = __builtin_amdgcn_mfma_f32_16x16x32_f16(Ahi[rt][1], S##l1, cr[rt], 0, 0, 0); \
        cr[rt] = __builtin_amdgcn_mfma_f32_16x16x32_f16(Alo[rt][0], S##h0, cr[rt], 0, 0, 0); \
        cr[rt] = __builtin_amdgcn_mfma_f32_16x16x32_f16(Alo[rt][1], S##h1, cr[rt], 0, 0, 0); \
    } \
    const int code_ = (tile) * 16 + n; \
    _Pragma("unroll") \
    for (int rt = 0; rt < 4; ++rt) \
        _Pragma("unroll") \
        for (int r = 0; r < 4; ++r) { \
            float s_ = fmaf(4.8828125e-4f, cr[rt][r], hh[rt][r]); \
            if (s_ < bd[rt][r]) { bd[rt][r] = s_; bi[rt][r] = code_; } \
        } }

    // prologue: tiles 0,1 in flight
    LOAD_SLOT(s0, 0)
    LOAD_SLOT(s1, 1)
    // steady state: each slot's loads issue TWO compute bodies before use (~650 cyc slack).
#pragma unroll 1
    for (int t = 0; t < 30; t += 3) {
        LOAD_SLOT(s2, t + 2)
        COMP_SLOT(s0, t)
        LOAD_SLOT(s0, t + 3)
        COMP_SLOT(s1, t + 1)
        LOAD_SLOT(s1, t + 4)
        COMP_SLOT(s2, t + 2)
    }
    COMP_SLOT(s0, 30)
    COMP_SLOT(s1, 31)
#undef DECL_SLOT
#undef LOAD_SLOT
#undef COMP_SLOT

    // ---- cross-lane argmin over the 16 code-columns (reduce over lane bits 0..3)
#pragma unroll
    for (int mask = 1; mask < 16; mask <<= 1) {
#pragma unroll
        for (int rt = 0; rt < 4; ++rt)
#pragma unroll
            for (int r = 0; r < 4; ++r) {
                float od = __shfl_xor(bd[rt][r], mask);
                int oi = __shfl_xor(bi[rt][r], mask);
                if (od < bd[rt][r] || (od == bd[rt][r] && oi < bi[rt][r])) { bd[rt][r] = od; bi[rt][r] = oi; }
            }
    }
    if (n == 0) {
#pragma unroll
        for (int rt = 0; rt < 4; ++rt)
#pragma unroll
            for (int r = 0; r < 4; ++r)
                idx_s[w * 64 + rt * 16 + g * 4 + r] = bi[rt][r];   // C-layout: row = g*4 + r
    }

    // ---- loss WITHOUT re-reading x: dist = bd_min + ||x||^2 (proven in round 2)
    float lsum = 0.f;
#pragma unroll
    for (int rt = 0; rt < 4; ++rt)
#pragma unroll
        for (int r = 0; r < 4; ++r) {
            float xv = __shfl(xx[rt], g * 4 + r);
            float dist = bd[rt][r] + xv;
            if (n == 0) lsum += dist;
        }
    __syncthreads();

    // ---- epilogue: gather q from ET (L2-hot), write coalesced. No x traffic.
#pragma unroll
    for (int p = 0; p < 4; ++p) {
        const int tok = p * 64 + (tid >> 2);
        const int part = tid & 3;
        const int gidx = idx_s[tok];
        const f32x4* ep = (const f32x4*)(ET + (size_t)gidx * D_DIM + part * 16);
        f32x4* qp = (f32x4*)(out_q + (size_t)(bt0 + tok) * D_DIM + part * 16);
#pragma unroll
        for (int u = 0; u < 4; ++u) qp[u] = ep[u];
    }

#pragma unroll
    for (int mask = 1; mask < 64; mask <<= 1) lsum += __shfl_xor(lsum, mask);
    if (l == 0) wsum_s[w] = lsum;
    __syncthreads();
    if (tid == 0) atomicAdd(out_loss, (wsum_s[0] + wsum_s[1] + wsum_s[2] + wsum_s[3]) * loss_scale);
}

// =================== round-1 fallback (proven) ===================
#define TOK_TILE 64
#define CHUNK 64
#define NCHUNK (K_CODES / CHUNK)
#define XS_STRIDE (TOK_TILE + 4)

__global__ __launch_bounds__(256, 4) void vq_fb_main(
        const float* __restrict__ x, const float* __restrict__ E,
        float* __restrict__ out_q, float* __restrict__ out_loss, float loss_scale) {
    __shared__ __align__(16) float Xs[D_DIM][XS_STRIDE];
    __shared__ __align__(16) float Es[D_DIM][CHUNK];
    __shared__ float ee_s[K_CODES];
    __shared__ int idx_s[TOK_TILE];
    __shared__ float wsum_s[4];

    const int tid = threadIdx.x;
    const int t0 = blockIdx.x * TOK_TILE;
    const int tx = tid & 15, ty = tid >> 4;
    const int ty4 = ty * 4, tx4 = tx * 4;

#pragma unroll
    for (int it = 0; it < 4; ++it) {
        int tl = it * 16 + (tid >> 4);
        int d0 = (tid & 15) * 4;
        float4 v = *(const float4*)(x + (size_t)(t0 + tl) * D_DIM + d0);
        Xs[d0 + 0][tl] = v.x; Xs[d0 + 1][tl] = v.y; Xs[d0 + 2][tl] = v.z; Xs[d0 + 3][tl] = v.w;
    }
    for (int k = tid; k < K_CODES; k += 256) {
        float s = 0.f;
#pragma unroll
        for (int d = 0; d < D_DIM; ++d) { float v = E[(size_t)d * K_CODES + k]; s = fmaf(v, v, s); }
        ee_s[k] = s;
    }

    float bd[4] = {3.4e38f, 3.4e38f, 3.4e38f, 3.4e38f};
    int bi[4] = {0, 0, 0, 0};

    for (int c = 0; c < NCHUNK; ++c) {
        __syncthreads();
#pragma unroll
        for (int ww = 0; ww < 4; ++ww) {
            int fidx = ww * 256 + tid;
            int d = fidx >> 4, k0 = (fidx & 15) * 4;
            float4 v = *(const float4*)(E + (size_t)d * K_CODES + c * CHUNK + k0);
            *(float4*)&Es[d][k0] = v;
        }
        __syncthreads();
        float acc[4][4] = {};
#pragma unroll
        for (int d = 0; d < D_DIM; ++d) {
            float4 a = *(const float4*)&Xs[d][ty4];
            float4 b = *(const float4*)&Es[d][tx4];
            acc[0][0] = fmaf(a.x, b.x, acc[0][0]); acc[0][1] = fmaf(a.x, b.y, acc[0][1]);
            acc[0][2] = fmaf(a.x, b.z, acc[0][2]); acc[0][3] = fmaf(a.x, b.w, acc[0][3]);
            acc[1][0] = fmaf(a.y, b.x, acc[1][0]); acc[1][1] = fmaf(a.y, b.y, acc[1][1]);
            acc[1][2] = fmaf(a.y, b.z, acc[1][2]); acc[1][3] = fmaf(a.y, b.w, acc[1][3]);
            acc[2][0] = fmaf(a.z, b.x, acc[2][0]); acc[2][1] = fmaf(a.z, b.y, acc[2][1]);
            acc[2][2] = fmaf(a.z, b.z, acc[2][2]); acc[2][3] = fmaf(a.z, b.w, acc[2][3]);
            acc[3][0] = fmaf(a.w, b.x, acc[3][0]); acc[3][1] = fmaf(a.w, b.y, acc[3][1]);
            acc[3][2] = fmaf(a.w, b.z, acc[3][2]); acc[3][3] = fmaf(a.w, b.w, acc[3][3]);
        }
        const int kbase = c * CHUNK + tx4;
#pragma unroll
        for (int i = 0; i < 4; ++i)
#pragma unroll
            for (int j = 0; j < 4; ++j) {
                float s = fmaf(-2.f, acc[i][j], ee_s[kbase + j]);
                if (s < bd[i]) { bd[i] = s; bi[i] = kbase + j; }
            }
    }
#pragma unroll
    for (int mask = 1; mask < 16; mask <<= 1)
#pragma unroll
        for (int i = 0; i < 4; ++i) {
            float od = __shfl_xor(bd[i], mask);
            int oi = __shfl_xor(bi[i], mask);
            if (od < bd[i] || (od == bd[i] && oi < bi[i])) { bd[i] = od; bi[i] = oi; }
        }
    if (tx == 0)
#pragma unroll
        for (int i = 0; i < 4; ++i) idx_s[ty4 + i] = bi[i];
    __syncthreads();

    const int tok = tid >> 2, part = tid & 3;
    const int gidx = idx_s[tok];
    const int gt = t0 + tok;
    float lsum = 0.f;
#pragma unroll
    for (int ww = 0; ww < 4; ++ww) {
        int o = part * 16 + ww * 4;
        float4 qv;
        qv.x = E[(size_t)(o + 0) * K_CODES + gidx];
        qv.y = E[(size_t)(o + 1) * K_CODES + gidx];
        qv.z = E[(size_t)(o + 2) * K_CODES + gidx];
        qv.w = E[(size_t)(o + 3) * K_CODES + gidx];
        float4 xv;
        xv.x = Xs[o + 0][tok]; xv.y = Xs[o + 1][tok]; xv.z = Xs[o + 2][tok]; xv.w = Xs[o + 3][tok];
        float dx = qv.x - xv.x, dy = qv.y - xv.y, dz = qv.z - xv.z, dw = qv.w - xv.w;
        lsum = fmaf(dx, dx, lsum); lsum = fmaf(dy, dy, lsum);
        lsum = fmaf(dz, dz, lsum); lsum = fmaf(dw, dw, lsum);
        *(float4*)(out_q + (size_t)gt * D_DIM + o) = qv;
    }
#pragma unroll
    for (int mask = 1; mask < 64; mask <<= 1) lsum += __shfl_xor(lsum, mask);
    if ((tid & 63) == 0) wsum_s[tid >> 6] = lsum;
    __syncthreads();
    if (tid == 0) atomicAdd(out_loss, (wsum_s[0] + wsum_s[1] + wsum_s[2] + wsum_s[3]) * loss_scale);
}

extern "C" void kernel_launch(void* const* d_in, const int* in_sizes, int n_in,
                              void* d_out, int out_size, void* d_ws, size_t ws_size,
                              hipStream_t stream) {
    const float* x = (const float*)d_in[0];   // [B,T,D] fp32
    const float* E = (const float*)d_in[1];   // [D,K] fp32
    float* out = (float*)d_out;
    const int n_tok = in_sizes[0] / D_DIM;    // 131072
    float* loss_ptr = out + (out_size - 1);
    const float loss_scale = 2.0f / (float)(n_tok * D_DIM);

    if (ws_size >= (size_t)WS_NEEDED) {
        float* ee = (float*)((char*)d_ws + WS_EE_OFF);
        float* ET = (float*)((char*)d_ws + WS_ET_OFF);
        _Float16* Bimg = (_Float16*)((char*)d_ws + WS_BIMG_OFF);
        vq3_prep<<<16, 256, 0, stream>>>(E, ee, ET, Bimg, loss_ptr);   // loss zeroed in prep
        vq3_main<<<n_tok / 256, 256, 0, stream>>>(x, ee, ET, Bimg, out, loss_ptr, loss_scale);
    } else {
        hipMemsetAsync(loss_ptr, 0, sizeof(float), stream);
        vq_fb_main<<<n_tok / TOK_TILE, 256, 0, stream>>>(x, E, out, loss_ptr, loss_scale);
    }
}